// Round 6
// baseline (7524.611 us; speedup 1.0000x reference)
//
#include <hip/hip_runtime.h>
#include <math.h>

typedef _Float16 f16;
typedef __attribute__((ext_vector_type(8))) _Float16 f16x8;
typedef __attribute__((ext_vector_type(4))) _Float16 f16x4;
typedef __attribute__((ext_vector_type(4))) float f32x4;

namespace {
constexpr int B_ = 1024, T_ = 168, H_ = 512, K_ = 8, TAU_ = 24;
}

__device__ __forceinline__ float sig_(float x) { return 1.0f / (1.0f + expf(-x)); }

__device__ __forceinline__ void gl16(const f16* g, char* l) {
    __builtin_amdgcn_global_load_lds((const __attribute__((address_space(1))) void*)g,
                                     (__attribute__((address_space(3))) void*)l, 16, 0, 0);
}
#define MFMA16 __builtin_amdgcn_mfma_f32_16x16x32_f16

struct CellA {
    const f16* Ain; long ldaIn; long KwIn; int ncIn;   // input-phase activations
    const f16* Wih;                                    // [2048][KwIn]
    const f16* Hh;                                     // recurrent h [B][512]
    const f16* Whh;                                    // [2048][512]
    const float* bsum;                                 // bih+bhh [2048]
    float* c;                                          // fp32 cell state [B][512]
    f16* oh;                                           // h out [B][512]
};
struct HeadA {
    const f16* h; const float* W1; const float* b1;
    const float* W2; const float* b2; float* out; int t; int active;
};

// gates = A@Wih^T + H@Whh^T (single fp16 product, fp32 MFMA accum) + LSTM epilogue.
// Block tile: 64 rows x 128 wrows (32 j x 4 gates). 4 waves 2x2, wave tile 32x64.
// BK=64, dbuf 48KB LDS, counted-vmcnt(6) 2-deep pipeline, XOR-swizzled tiles.
// Blocks with id >= nblk run the fused mu/sigma head (decoder only).
extern "C" __global__ void __launch_bounds__(256, 2)
cell_kernel(CellA a0, CellA a1, HeadA hd, int nblk, int two)
{
    __shared__ char lds[49152];       // 2 bufs x {A 8K | W 16K}
    const int tid = threadIdx.x;
    const int id  = blockIdx.x;

    if (id >= nblk) {                 // ---- fused head path ----
        if (!hd.active) return;
        const int gidx = (id - nblk) * 256 + tid;
        #pragma unroll
        for (int rep = 0; rep < 4; ++rep) {
            const int idx = gidx + 4096 * rep;
            const int b = idx >> 4, rr = idx & 15, k = rr & 7, which = rr >> 3;
            const float* w  = (which ? hd.W2 : hd.W1) + (long)k * H_;
            const f16*   hp = hd.h + (long)b * H_;
            float sum = 0.f;
            for (int d = 0; d < H_; d += 8) {
                f16x8  hv = *(const f16x8*)&hp[d];
                float4 w0 = *(const float4*)&w[d];
                float4 w1 = *(const float4*)&w[d + 4];
                sum = fmaf((float)hv[0], w0.x, sum);
                sum = fmaf((float)hv[1], w0.y, sum);
                sum = fmaf((float)hv[2], w0.z, sum);
                sum = fmaf((float)hv[3], w0.w, sum);
                sum = fmaf((float)hv[4], w1.x, sum);
                sum = fmaf((float)hv[5], w1.y, sum);
                sum = fmaf((float)hv[6], w1.z, sum);
                sum = fmaf((float)hv[7], w1.w, sum);
            }
            const long o = ((long)b * TAU_ + hd.t) * K_ + k;
            if (which == 0) {
                hd.out[o] = sum + hd.b1[k];
            } else {
                float z  = 2.0f * (sum + hd.b2[k]);
                float sp = fmaxf(z, 0.0f) + log1pf(expf(-fabsf(z)));
                hd.out[(long)B_ * TAU_ * K_ + o] = 0.5f * sp;
            }
        }
        return;
    }

    // ---- cell path ----
    // bijective XCD-chunked remap; staggered cells interleaved within each XCD
    const int id2 = (id & 7) * (nblk >> 3) + (id >> 3);
    int cell, rem;
    if (two) { cell = id2 & 1; rem = id2 >> 1; }
    else     { cell = 0;       rem = id2; }
    const CellA& A = cell ? a1 : a0;
    const int row0 = (rem & 15) * 64;         // 16 M-tiles
    const int j0   = (rem >> 4) * 32;         // 16 N-tiles

    const int lane = tid & 63, wid = tid >> 6;
    const int l16 = lane & 15, lq = lane >> 4;
    const int wr = wid >> 1, wc = wid & 1;

    // ---- staging geometry (pre-swizzled global source) ----
    const int  sr  = tid >> 3, sl = tid & 7;
    const long ksw = (long)((sl ^ (sr & 7)) << 3);       // element offset
    long aIn[2], aR[2], wIn[4], wR[4];
    #pragma unroll
    for (int p = 0; p < 2; ++p) {
        aIn[p] = (long)(row0 + sr + 32 * p) * A.ldaIn + ksw;
        aR[p]  = (long)(row0 + sr + 32 * p) * H_ + ksw;
    }
    #pragma unroll
    for (int q = 0; q < 4; ++q) {
        const int r = sr + 32 * q;
        const long grow = (long)(((r >> 4) & 3) * H_ + j0 + ((r >> 6) << 4) + (r & 15));
        wIn[q] = grow * A.KwIn + ksw;
        wR[q]  = grow * H_ + ksw;
    }
    const int ncIn = A.ncIn;
    const int NC   = ncIn + (H_ >> 6);

    auto stageChunk = [&](int ci) {
        char* lb = lds + (ci & 1) * 24576;
        if (ci < ncIn) {
            const long k0 = (long)ci << 6;
            gl16(A.Ain + aIn[0] + k0, lb + tid * 16);
            gl16(A.Ain + aIn[1] + k0, lb + 4096 + tid * 16);
            gl16(A.Wih + wIn[0] + k0, lb + 8192  + tid * 16);
            gl16(A.Wih + wIn[1] + k0, lb + 12288 + tid * 16);
            gl16(A.Wih + wIn[2] + k0, lb + 16384 + tid * 16);
            gl16(A.Wih + wIn[3] + k0, lb + 20480 + tid * 16);
        } else {
            const long k0 = (long)(ci - ncIn) << 6;
            gl16(A.Hh  + aR[0] + k0, lb + tid * 16);
            gl16(A.Hh  + aR[1] + k0, lb + 4096 + tid * 16);
            gl16(A.Whh + wR[0] + k0, lb + 8192  + tid * 16);
            gl16(A.Whh + wR[1] + k0, lb + 12288 + tid * 16);
            gl16(A.Whh + wR[2] + k0, lb + 16384 + tid * 16);
            gl16(A.Whh + wR[3] + k0, lb + 20480 + tid * 16);
        }
    };

    // ---- compute geometry ----
    const int swz = (l16 & 7) << 4;
    const int ab0 = (wr * 32 + l16) * 128;          // m=0 A row (bytes)
    const int ab1 = ab0 + 16 * 128;                 // m=1
    int wb[4];
    #pragma unroll
    for (int nf = 0; nf < 4; ++nf) wb[nf] = (wc * 64 + nf * 16 + l16) * 128;

    f32x4 acc[4][2];
    #pragma unroll
    for (int nf = 0; nf < 4; ++nf)
        #pragma unroll
        for (int m = 0; m < 2; ++m)
            #pragma unroll
            for (int q = 0; q < 4; ++q) acc[nf][m][q] = 0.f;

    // ---- 2-deep counted-vmcnt pipeline ----
    stageChunk(0);
    stageChunk(1);                                  // NC >= 9 always
    for (int i = 0; i < NC; ++i) {
        if (i + 1 < NC) asm volatile("s_waitcnt vmcnt(6)" ::: "memory");
        else            asm volatile("s_waitcnt vmcnt(0)" ::: "memory");
        __builtin_amdgcn_s_barrier();               // chunk i visible to all waves

        char* lb = lds + (i & 1) * 24576;
        #pragma unroll
        for (int ks = 0; ks < 2; ++ks) {
            const int kb = ((ks * 64) + lq * 16) ^ swz;
            f16x8 ah0 = *(const f16x8*)(lb + ab0 + kb);
            f16x8 ah1 = *(const f16x8*)(lb + ab1 + kb);
            #pragma unroll
            for (int nf = 0; nf < 4; ++nf) {
                f16x8 wv = *(const f16x8*)(lb + 8192 + wb[nf] + kb);
                acc[nf][0] = MFMA16(ah0, wv, acc[nf][0], 0, 0, 0);
                acc[nf][1] = MFMA16(ah1, wv, acc[nf][1], 0, 0, 0);
            }
        }

        asm volatile("s_waitcnt lgkmcnt(0)" ::: "memory");
        __builtin_amdgcn_s_barrier();               // no wave still reads buf[i&1]
        if (i + 2 < NC) stageChunk(i + 2);
    }

    // ---- epilogue: all 4 gates in-lane ----
    const int j = j0 + wc * 16 + l16;
    float bs[4];
    #pragma unroll
    for (int g = 0; g < 4; ++g) bs[g] = A.bsum[g * H_ + j];
    #pragma unroll
    for (int m = 0; m < 2; ++m)
        #pragma unroll
        for (int r = 0; r < 4; ++r) {
            const int  b    = row0 + wr * 32 + m * 16 + lq * 4 + r;
            const long base = (long)b * H_ + j;
            const float cold = A.c[base];
            const float pi = acc[0][m][r] + bs[0];
            const float pf = acc[1][m][r] + bs[1];
            const float pg = acc[2][m][r] + bs[2];
            const float po = acc[3][m][r] + bs[3];
            const float cn = sig_(pf) * cold + sig_(pi) * tanhf(pg);
            const float hn = sig_(po) * tanhf(cn);
            A.c[base] = cn;
            A.oh[base] = (f16)hn;
        }
}

// x[B][T][32] fp32 -> xp[t][B][64] fp16 zero-padded
extern "C" __global__ void __launch_bounds__(256)
padx_kernel(const float* __restrict__ x, f16* __restrict__ xp)
{
    const int idx = blockIdx.x * 256 + threadIdx.x;     // t*B + b
    const int t = idx >> 10, b = idx & 1023;
    const float* src = x + ((long)b * T_ + t) * 32;
    f16* dst = xp + (long)idx * 64;
    #pragma unroll
    for (int q = 0; q < 8; ++q) {
        float4 v = *(const float4*)&src[q * 4];
        *(f16x4*)&dst[q * 4] = (f16x4){(f16)v.x, (f16)v.y, (f16)v.z, (f16)v.w};
    }
    #pragma unroll
    for (int q = 8; q < 16; ++q) *(f16x4*)&dst[q * 4] = (f16x4){0, 0, 0, 0};
}

// eWih0 [2048][32] fp32 -> [2048][64] fp16 zero-padded
extern "C" __global__ void __launch_bounds__(256)
padw_kernel(const float* __restrict__ w, f16* __restrict__ dst)
{
    const int idx = blockIdx.x * 256 + threadIdx.x;     // row*16 + k4
    const int row = idx >> 4, k4 = idx & 15;
    f16x4 hv = (f16x4){0, 0, 0, 0};
    if (k4 < 8) {
        float4 v = *(const float4*)&w[(long)row * 32 + k4 * 4];
        hv = (f16x4){(f16)v.x, (f16)v.y, (f16)v.z, (f16)v.w};
    }
    *(f16x4*)&dst[(long)row * 64 + k4 * 4] = hv;
}

// 7 x [2048][512] fp32 -> fp16, contiguous regions of dst
extern "C" __global__ void __launch_bounds__(256)
wcvt_kernel(const float* s0, const float* s1, const float* s2, const float* s3,
            const float* s4, const float* s5, const float* s6, f16* dst)
{
    const int i = blockIdx.x * 256 + threadIdx.x;       // float4 index
    if (i >= 7 * 262144) return;
    const int m = i >> 18, off = i & 262143;
    const float* s = m == 0 ? s0 : m == 1 ? s1 : m == 2 ? s2 : m == 3 ? s3
                   : m == 4 ? s4 : m == 5 ? s5 : s6;
    float4 v = ((const float4*)s)[off];
    *(f16x4*)&dst[(long)m * 1048576 + (long)off * 4] =
        (f16x4){(f16)v.x, (f16)v.y, (f16)v.z, (f16)v.w};
}

extern "C" __global__ void __launch_bounds__(256)
bias_kernel(const float* a0, const float* b0, const float* a1, const float* b1,
            const float* a2, const float* b2, const float* a3, const float* b3,
            float* out)   // out[4][2048]
{
    const int i = blockIdx.x * 256 + threadIdx.x;
    const int l = i >> 11, k = i & 2047;
    const float* pa = l == 0 ? a0 : l == 1 ? a1 : l == 2 ? a2 : a3;
    const float* pb = l == 0 ? b0 : l == 1 ? b1 : l == 2 ? b2 : b3;
    out[i] = pa[k] + pb[k];
}

extern "C" __global__ void __launch_bounds__(256)
zero16(uint4* p, int n)
{
    for (int i = blockIdx.x * 256 + threadIdx.x; i < n; i += gridDim.x * 256)
        p[i] = make_uint4(0, 0, 0, 0);
}

extern "C" void kernel_launch(void* const* d_in, const int* in_sizes, int n_in,
                              void* d_out, int out_size, void* d_ws, size_t ws_size,
                              hipStream_t stream)
{
    (void)in_sizes; (void)n_in; (void)out_size; (void)ws_size;

    const float* x     = (const float*)d_in[0];
    const float* eWih0 = (const float*)d_in[1];
    const float* eWhh0 = (const float*)d_in[2];
    const float* ebih0 = (const float*)d_in[3];
    const float* ebhh0 = (const float*)d_in[4];
    const float* eWih1 = (const float*)d_in[5];
    const float* eWhh1 = (const float*)d_in[6];
    const float* ebih1 = (const float*)d_in[7];
    const float* ebhh1 = (const float*)d_in[8];
    const float* dWih0 = (const float*)d_in[9];
    const float* dWhh0 = (const float*)d_in[10];
    const float* dbih0 = (const float*)d_in[11];
    const float* dbhh0 = (const float*)d_in[12];
    const float* dWih1 = (const float*)d_in[13];
    const float* dWhh1 = (const float*)d_in[14];
    const float* dbih1 = (const float*)d_in[15];
    const float* dbhh1 = (const float*)d_in[16];
    const float* W1    = (const float*)d_in[17];
    const float* b1    = (const float*)d_in[18];
    const float* W2    = (const float*)d_in[19];
    const float* b2    = (const float*)d_in[20];
    float* out = (float*)d_out;

    char* wsp = (char*)d_ws;
    auto take = [&](size_t n) { void* p = (void*)wsp; wsp += n; return p; };

    f16* xp   = (f16*)take((size_t)T_ * B_ * 64 * 2);
    f16* w0p  = (f16*)take((size_t)2048 * 64 * 2);
    f16* wsW  = (f16*)take((size_t)7 * 2048 * 512 * 2);
    float* bsum = (float*)take((size_t)4 * 2048 * 4);

    const size_t NH = (size_t)B_ * H_;
    char* zstart = wsp;
    f16 *h0[2], *h1[2];
    for (int p = 0; p < 2; ++p) h0[p] = (f16*)take(NH * 2);
    for (int p = 0; p < 2; ++p) h1[p] = (f16*)take(NH * 2);
    float* c0 = (float*)take(NH * 4);
    float* c1 = (float*)take(NH * 4);
    const size_t zeroBytes = (size_t)(wsp - zstart);

    const dim3 blk(256);

    padx_kernel<<<dim3(T_ * B_ / 256), blk, 0, stream>>>(x, xp);
    padw_kernel<<<dim3(128), blk, 0, stream>>>(eWih0, w0p);
    wcvt_kernel<<<dim3(7168), blk, 0, stream>>>(eWhh0, eWih1, eWhh1, dWih0,
                                                dWhh0, dWih1, dWhh1, wsW);
    bias_kernel<<<dim3(32), blk, 0, stream>>>(ebih0, ebhh0, ebih1, ebhh1,
                                              dbih0, dbhh0, dbih1, dbhh1, bsum);
    zero16<<<dim3(2048), blk, 0, stream>>>((uint4*)zstart, (int)(zeroBytes / 16));

    const size_t WM = (size_t)2048 * 512;
    auto mkL0e = [&](int t, int pin, int pout) {
        CellA c; c.Ain = xp + (size_t)t * B_ * 64; c.ldaIn = 64; c.KwIn = 64; c.ncIn = 1;
        c.Wih = w0p; c.Hh = h0[pin]; c.Whh = wsW;
        c.bsum = bsum; c.c = c0; c.oh = h0[pout]; return c;
    };
    auto mkL1e = [&](int pa, int pin, int pout) {
        CellA c; c.Ain = h0[pa]; c.ldaIn = H_; c.KwIn = H_; c.ncIn = 8;
        c.Wih = wsW + WM; c.Hh = h1[pin]; c.Whh = wsW + 2 * WM;
        c.bsum = bsum + 2048; c.c = c1; c.oh = h1[pout]; return c;
    };
    auto mkL0d = [&](int pa, int pin, int pout) {
        CellA c; c.Ain = h1[pa]; c.ldaIn = H_; c.KwIn = H_; c.ncIn = 8;
        c.Wih = wsW + 3 * WM; c.Hh = h0[pin]; c.Whh = wsW + 4 * WM;
        c.bsum = bsum + 4096; c.c = c0; c.oh = h0[pout]; return c;
    };
    auto mkL1d = [&](int pa, int pin, int pout) {
        CellA c; c.Ain = h0[pa]; c.ldaIn = H_; c.KwIn = H_; c.ncIn = 8;
        c.Wih = wsW + 5 * WM; c.Hh = h1[pin]; c.Whh = wsW + 6 * WM;
        c.bsum = bsum + 6144; c.c = c1; c.oh = h1[pout]; return c;
    };

    HeadA hz; hz.h = h1[0]; hz.W1 = W1; hz.b1 = b1; hz.W2 = W2; hz.b2 = b2;
    hz.out = out; hz.t = 0; hz.active = 0;

    int p0 = 1, p1 = 1;     // zeros live in buffer 1

    { CellA a = mkL0e(0, p0, p0 ^ 1);
      cell_kernel<<<dim3(256), blk, 0, stream>>>(a, a, hz, 256, 0); p0 ^= 1; }

    for (int t = 0; t < T_ - 1; ++t) {              // stagger: L1(t) || L0(t+1)
        CellA l1 = mkL1e(p0, p1, p1 ^ 1);
        CellA l0 = mkL0e(t + 1, p0, p0 ^ 1);
        cell_kernel<<<dim3(512), blk, 0, stream>>>(l1, l0, hz, 512, 1);
        p0 ^= 1; p1 ^= 1;
    }
    { CellA a = mkL1e(p0, p1, p1 ^ 1);
      cell_kernel<<<dim3(256), blk, 0, stream>>>(a, a, hz, 256, 0); p1 ^= 1; }

    for (int t = 0; t < TAU_; ++t) {
        HeadA hp = hz;
        if (t > 0) { hp.h = h1[p1]; hp.t = t - 1; hp.active = 1; }
        CellA a = mkL0d(p1, p0, p0 ^ 1);
        cell_kernel<<<dim3(272), blk, 0, stream>>>(a, a, hp, 256, 0); p0 ^= 1;
        CellA b_ = mkL1d(p0, p1, p1 ^ 1);
        cell_kernel<<<dim3(256), blk, 0, stream>>>(b_, b_, hz, 256, 0); p1 ^= 1;
    }
    { HeadA hp = hz; hp.h = h1[p1]; hp.t = TAU_ - 1; hp.active = 1;
      CellA a = mkL1d(p0, p1, p1);   // dummy cell args (nblk=0: head-only)
      cell_kernel<<<dim3(16), blk, 0, stream>>>(a, a, hp, 0, 0); }
}